// Round 6
// baseline (94.676 us; speedup 1.0000x reference)
//
#include <hip/hip_runtime.h>
#include <cstdint>

#define E_EDGES 400000
#define N_NODES 25000
#define NG32    12500          // groups of 32 edges
#define NTILES  33             // 32 W2 K-tiles + 1 b2 tile (K=16 each)
#define NPACKB  (NTILES*64*8)  // 16896 ushorts: B-frags [kt][lane][j]
#define NPACKA  512            // aw frag (W1^T as 32x32x16 A operand)
#define NPACKT  (NPACKB+NPACKA)
#define EBLOCKS 1042
#define ESTRIDE (EBLOCKS*4)    // 4168 waves, <=3 groups each

typedef float  f32x4  __attribute__((ext_vector_type(4)));
typedef float  f32x16 __attribute__((ext_vector_type(16)));
typedef __bf16 bf16x8 __attribute__((ext_vector_type(8)));

static __device__ __forceinline__ ushort f2bf(float f) {
    union { __bf16 b; ushort u; } c; c.b = (__bf16)f; return c.u;
}

// ---------------------------------------------------------------------------
// K_pack: W2/b2 -> 33 B-frags for mfma_32x32x16 (with the m-permutation that
// matches the h-MFMA C layout), W1^T -> one A-frag. Plus dst histogram.
//   B-frag[kt][lane][j]:
//     kt<32: i=kt>>1, p=kt&1, m=(j&3)+8*(2p+(j>>2))+4*(lane>>5)
//            val = W2[m][i*32 + (lane&31)]
//     kt==32: k=(lane>>5)*8+j, val = b2[k*32 + (lane&31)]
//   A-frag[lane][j]: hi=lane>>5; hi==0 -> W1[j][lane&31] else 0
// ---------------------------------------------------------------------------
__global__ void __launch_bounds__(256) k_pack(const float* __restrict__ W2,
                                              const float* __restrict__ b2,
                                              const float* __restrict__ W1,
                                              const int* __restrict__ ei,
                                              ushort* __restrict__ packed,
                                              uint* __restrict__ cnt_u) {
    int t = blockIdx.x * 256 + threadIdx.x;
    if (t < NPACKT) {
        float v = 0.0f;
        if (t < NPACKB) {
            int j = t & 7, lane = (t >> 3) & 63, kt = t >> 9;
            int o = lane & 31, hi = lane >> 5;
            if (kt < 32) {
                int i = kt >> 1, p = kt & 1;
                int m = (j & 3) + 8 * (2 * p + (j >> 2)) + 4 * hi;
                v = W2[m * 512 + i * 32 + o];
            } else {
                int k = hi * 8 + j;
                v = b2[k * 32 + o];
            }
        } else {
            int t2 = t - NPACKB;
            int j = t2 & 7, lane = t2 >> 3;
            int m = lane & 31, hi = lane >> 5;
            if (hi == 0) v = W1[j * 32 + m];
        }
        packed[t] = f2bf(v);
    }
    if (t < E_EDGES) atomicAdd(&cnt_u[ei[E_EDGES + t]], 1u);
}

// ---------------------------------------------------------------------------
// K_edge: 32 edges/group via mfma_f32_32x32x16_bf16.
//   h = relu(ea@W1+b1): ONE h-MFMA -> C[m, e=lane&31], rg = p*8+j feeds tiles
//   msg = A'[32e x 528] @ W2'[528 x 32]: 33 tiles, A built in registers
//   2-level pipeline: ei two groups ahead, ea/x one body ahead.
// ---------------------------------------------------------------------------
__global__ void __launch_bounds__(256) k_edge(const float* __restrict__ ea,
                                              const float* __restrict__ x,
                                              const int* __restrict__ ei,
                                              const ushort* __restrict__ packed,
                                              const float* __restrict__ b1,
                                              float* __restrict__ agg) {
    __shared__ alignas(16) ushort bl[NPACKB];
    {
        const uint4* s = (const uint4*)packed;
        uint4* d = (uint4*)bl;
        for (int i = threadIdx.x; i < NPACKB / 8; i += 256) d[i] = s[i];
    }
    __syncthreads();

    const int lane = threadIdx.x & 63;
    const int o  = lane & 31;        // A-row edge, C col, B col
    const int hi = lane >> 5;
    const int wid = blockIdx.x * 4 + (threadIdx.x >> 6);

    // loop-invariants
    const bf16x8 aw = *(const bf16x8*)(packed + NPACKB + (size_t)lane * 8);
    const f32x4 b1q0 = *(const f32x4*)(b1 + 0  + 4 * hi);
    const f32x4 b1q1 = *(const f32x4*)(b1 + 8  + 4 * hi);
    const f32x4 b1q2 = *(const f32x4*)(b1 + 16 + 4 * hi);
    const f32x4 b1q3 = *(const f32x4*)(b1 + 24 + 4 * hi);

    const f32x16 z16 = {0.f,0.f,0.f,0.f,0.f,0.f,0.f,0.f,0.f,0.f,0.f,0.f,0.f,0.f,0.f,0.f};
    const f32x4  z4  = {0.f,0.f,0.f,0.f};
    const __bf16 zb = (__bf16)0.0f;

    // ---- prologue
    int g = wid;                             // wid < 4168 <= NG32
    f32x4 ea0, ea1, xq0, xq1, xq2, xq3;
    int s_nxt = 0;
    {
        const int e = g * 32 + o;
        const int s_cur = ei[e];
        const f32x4* ep = (const f32x4*)(ea + (size_t)e * 8);
        ea0 = ep[0]; ea1 = ep[1];
        const f32x4* xp = (const f32x4*)(x + (size_t)s_cur * 16);
        xq0 = xp[0]; xq1 = xp[1]; xq2 = xp[2]; xq3 = xp[3];
        const int gnx = g + ESTRIDE;
        if (gnx < NG32) s_nxt = ei[gnx * 32 + o];
    }

    while (true) {
        const int gn = g + ESTRIDE;
        const bool pf = gn < NG32;

        // ---- issue next body's ea + x (s_nxt arrived last body) + ei 2-ahead
        f32x4 nea0 = z4, nea1 = z4, nx0 = z4, nx1 = z4, nx2 = z4, nx3 = z4;
        int s_nn = 0;
        if (pf) {
            const f32x4* nep = (const f32x4*)(ea + (size_t)(gn * 32 + o) * 8);
            nea0 = nep[0]; nea1 = nep[1];
            const f32x4* nxp = (const f32x4*)(x + (size_t)s_nxt * 16);
            nx0 = nxp[0]; nx1 = nxp[1]; nx2 = nxp[2]; nx3 = nxp[3];
            const int gnn = gn + ESTRIDE;
            if (gnn < NG32) s_nn = ei[gnn * 32 + o];
        }
        // dsts for my 16 C rows: edge = (rg&3) + 8*(rg>>2) + 4*hi
        const int4 dq0 = *(const int4*)(ei + E_EDGES + g * 32 + 0  + 4 * hi);
        const int4 dq1 = *(const int4*)(ei + E_EDGES + g * 32 + 8  + 4 * hi);
        const int4 dq2 = *(const int4*)(ei + E_EDGES + g * 32 + 16 + 4 * hi);
        const int4 dq3 = *(const int4*)(ei + E_EDGES + g * 32 + 24 + 4 * hi);

        // ---- h-MFMA: A = W1^T, B = ea^T (hi==0 lanes carry data)
        bf16x8 eb;
        if (hi == 0) {
            eb[0]=(__bf16)ea0[0]; eb[1]=(__bf16)ea0[1]; eb[2]=(__bf16)ea0[2]; eb[3]=(__bf16)ea0[3];
            eb[4]=(__bf16)ea1[0]; eb[5]=(__bf16)ea1[1]; eb[6]=(__bf16)ea1[2]; eb[7]=(__bf16)ea1[3];
        } else {
            eb[0]=zb; eb[1]=zb; eb[2]=zb; eb[3]=zb; eb[4]=zb; eb[5]=zb; eb[6]=zb; eb[7]=zb;
        }
        const f32x16 hC = __builtin_amdgcn_mfma_f32_32x32x16_bf16(aw, eb, z16, 0, 0, 0);

        float hreg[16];
        hreg[0]  = fmaxf(hC[0]  + b1q0[0], 0.f);
        hreg[1]  = fmaxf(hC[1]  + b1q0[1], 0.f);
        hreg[2]  = fmaxf(hC[2]  + b1q0[2], 0.f);
        hreg[3]  = fmaxf(hC[3]  + b1q0[3], 0.f);
        hreg[4]  = fmaxf(hC[4]  + b1q1[0], 0.f);
        hreg[5]  = fmaxf(hC[5]  + b1q1[1], 0.f);
        hreg[6]  = fmaxf(hC[6]  + b1q1[2], 0.f);
        hreg[7]  = fmaxf(hC[7]  + b1q1[3], 0.f);
        hreg[8]  = fmaxf(hC[8]  + b1q2[0], 0.f);
        hreg[9]  = fmaxf(hC[9]  + b1q2[1], 0.f);
        hreg[10] = fmaxf(hC[10] + b1q2[2], 0.f);
        hreg[11] = fmaxf(hC[11] + b1q2[3], 0.f);
        hreg[12] = fmaxf(hC[12] + b1q3[0], 0.f);
        hreg[13] = fmaxf(hC[13] + b1q3[1], 0.f);
        hreg[14] = fmaxf(hC[14] + b1q3[2], 0.f);
        hreg[15] = fmaxf(hC[15] + b1q3[3], 0.f);

        float xr[16];
        xr[0]=xq0[0]; xr[1]=xq0[1]; xr[2]=xq0[2]; xr[3]=xq0[3];
        xr[4]=xq1[0]; xr[5]=xq1[1]; xr[6]=xq1[2]; xr[7]=xq1[3];
        xr[8]=xq2[0]; xr[9]=xq2[1]; xr[10]=xq2[2]; xr[11]=xq2[3];
        xr[12]=xq3[0]; xr[13]=xq3[1]; xr[14]=xq3[2]; xr[15]=xq3[3];

        f32x16 acc = z16;

        // ---- main GEMM: 32 W2 tiles; tile kt uses x_i (i=kt>>1) and hreg[8p+j]
#pragma unroll
        for (int kt = 0; kt < 32; ++kt) {
            const int p = kt & 1;
            const float xv = xr[kt >> 1];
            bf16x8 a;
#pragma unroll
            for (int j = 0; j < 8; ++j) a[j] = (__bf16)(xv * hreg[p * 8 + j]);
            const bf16x8 bf = *(const bf16x8*)(&bl[kt * 512 + lane * 8]);
            acc = __builtin_amdgcn_mfma_f32_32x32x16_bf16(a, bf, acc, 0, 0, 0);
        }
        { // b2 tile: A[e,k] = x[e,k], k = hi*8+j
            bf16x8 a;
#pragma unroll
            for (int j = 0; j < 8; ++j) a[j] = (__bf16)(hi ? xr[8 + j] : xr[j]);
            const bf16x8 bf = *(const bf16x8*)(&bl[32 * 512 + lane * 8]);
            acc = __builtin_amdgcn_mfma_f32_32x32x16_bf16(a, bf, acc, 0, 0, 0);
        }

        // ---- scatter: C[edge=(rg&3)+8*(rg>>2)+4hi, col=o]
        atomicAdd(&agg[dq0.x * 32 + o], acc[0]);
        atomicAdd(&agg[dq0.y * 32 + o], acc[1]);
        atomicAdd(&agg[dq0.z * 32 + o], acc[2]);
        atomicAdd(&agg[dq0.w * 32 + o], acc[3]);
        atomicAdd(&agg[dq1.x * 32 + o], acc[4]);
        atomicAdd(&agg[dq1.y * 32 + o], acc[5]);
        atomicAdd(&agg[dq1.z * 32 + o], acc[6]);
        atomicAdd(&agg[dq1.w * 32 + o], acc[7]);
        atomicAdd(&agg[dq2.x * 32 + o], acc[8]);
        atomicAdd(&agg[dq2.y * 32 + o], acc[9]);
        atomicAdd(&agg[dq2.z * 32 + o], acc[10]);
        atomicAdd(&agg[dq2.w * 32 + o], acc[11]);
        atomicAdd(&agg[dq3.x * 32 + o], acc[12]);
        atomicAdd(&agg[dq3.y * 32 + o], acc[13]);
        atomicAdd(&agg[dq3.z * 32 + o], acc[14]);
        atomicAdd(&agg[dq3.w * 32 + o], acc[15]);

        if (!pf) break;
        g = gn;
        ea0 = nea0; ea1 = nea1;
        xq0 = nx0; xq1 = nx1; xq2 = nx2; xq3 = nx3;
        s_nxt = s_nn;
    }
}

// ---------------------------------------------------------------------------
// K_node: fused  a = relu(agg/cnt + x@root + bias)  then  out = a@Wlin + blin
// ---------------------------------------------------------------------------
__global__ void __launch_bounds__(256) k_node(const float* __restrict__ agg,
                                              const uint* __restrict__ cnt_u,
                                              const float* __restrict__ x,
                                              const float* __restrict__ root,
                                              const float* __restrict__ bias,
                                              const float* __restrict__ Wlin,
                                              const float* __restrict__ blin,
                                              float* __restrict__ out) {
    __shared__ float al[256];
    const int n0 = blockIdx.x * 8;
    const int t = threadIdx.x;
    const int n = n0 + (t >> 5), h = t & 31;
    float a = 0.0f;
    if (n < N_NODES) {
        const float c = (float)cnt_u[n];
        float s = agg[n * 32 + h] / fmaxf(c, 1.0f) + bias[h];
        const f32x4* xp = (const f32x4*)(x + (size_t)n * 16);
        const f32x4 x0 = xp[0], x1 = xp[1], x2 = xp[2], x3 = xp[3];
        float xv[16];
        xv[0]=x0[0]; xv[1]=x0[1]; xv[2]=x0[2]; xv[3]=x0[3];
        xv[4]=x1[0]; xv[5]=x1[1]; xv[6]=x1[2]; xv[7]=x1[3];
        xv[8]=x2[0]; xv[9]=x2[1]; xv[10]=x2[2]; xv[11]=x2[3];
        xv[12]=x3[0]; xv[13]=x3[1]; xv[14]=x3[2]; xv[15]=x3[3];
#pragma unroll
        for (int i = 0; i < 16; ++i) s += xv[i] * root[i * 32 + h];
        a = fmaxf(s, 0.0f);
    }
    al[t] = a;
    __syncthreads();
    if (t < 128) {
        const int nj = n0 + (t >> 4), j = t & 15;
        if (nj < N_NODES) {
            float s = blin[j];
#pragma unroll
            for (int h2 = 0; h2 < 32; ++h2) s += al[(t >> 4) * 32 + h2] * Wlin[h2 * 16 + j];
            out[nj * 16 + j] = s;
        }
    }
}

// ---------------------------------------------------------------------------
extern "C" void kernel_launch(void* const* d_in, const int* in_sizes, int n_in,
                              void* d_out, int out_size, void* d_ws, size_t ws_size,
                              hipStream_t stream) {
    const float* x    = (const float*)d_in[0];
    const float* ea   = (const float*)d_in[1];
    const float* W1   = (const float*)d_in[2];
    const float* b1   = (const float*)d_in[3];
    const float* W2   = (const float*)d_in[4];
    const float* b2   = (const float*)d_in[5];
    const float* root = (const float*)d_in[6];
    const float* bias = (const float*)d_in[7];
    const float* Wlin = (const float*)d_in[8];
    const float* blin = (const float*)d_in[9];
    const int*   ei   = (const int*)d_in[10];
    float* out = (float*)d_out;

    char* ws = (char*)d_ws;
    float*  agg    = (float*)(ws + 0);           // 3,200,000
    uint*   cnt_u  = (uint*)(ws + 3200000);      //   100,000
    ushort* packed = (ushort*)(ws + 3300000);    //    34,816

    hipMemsetAsync(d_ws, 0, 3300000, stream);    // agg + cnt_u

    k_pack<<<1563, 256, 0, stream>>>(W2, b2, W1, ei, packed, cnt_u);
    k_edge<<<EBLOCKS, 256, 0, stream>>>(ea, x, ei, packed, b1, agg);
    k_node<<<3125, 256, 0, stream>>>(agg, cnt_u, x, root, bias, Wlin, blin, out);
}